// Round 5
// baseline (298.894 us; speedup 1.0000x reference)
//
#include <hip/hip_runtime.h>

#define D   256
#define BM  64      // rows per block
#define BN  128     // codes per LDS chunk
#define KC  64      // k per LDS chunk (2 MFMA k-steps); 4 chunks per full K

typedef __attribute__((ext_vector_type(8))) short v8s;   // 8 bf16 = 4 VGPR
typedef __attribute__((ext_vector_type(4))) float v4f;
#define MFMA16 __builtin_amdgcn_mfma_f32_16x16x32_bf16

static __device__ inline unsigned short f2bf(float f) {          // RNE
    unsigned u = __float_as_uint(f);
    return (unsigned short)((u + 0x7fffu + ((u >> 16) & 1u)) >> 16);
}
static __device__ inline float bf2f(unsigned short s) {
    return __uint_as_float(((unsigned)s) << 16);
}

// async global->LDS, 16 B per lane. LDS dest must be wave-uniform (HW adds lane*16).
static __device__ inline void gl_lds16(const unsigned short* g, unsigned short* l) {
    __builtin_amdgcn_global_load_lds(
        (const __attribute__((address_space(1))) unsigned int*)g,
        (__attribute__((address_space(3))) unsigned int*)l, 16, 0, 0);
}

// ---------------- kernel 1a: exact c2 ----------------
__global__ void vq_prep_c2(const float* __restrict__ cb, float* __restrict__ c2) {
    const int row  = blockIdx.x;
    const int lane = threadIdx.x;  // 64
    const float4 v = *reinterpret_cast<const float4*>(cb + (size_t)row * D + lane * 4);
    float s = v.x * v.x + v.y * v.y + v.z * v.z + v.w * v.w;
    #pragma unroll
    for (int off = 32; off > 0; off >>= 1) s += __shfl_down(s, off, 64);
    if (lane == 0) c2[row] = s;
}

// ---------------- kernel 1b: codebook -> bf16 hi/lo, chunk-major pre-swizzled ----------------
// Chunk (nc_i, kc_i) = 128 codes x 64 k = 1024 granules of 16 B (8 bf16).
// Granule p within chunk: seg = p>>7 (k-octet), q = p&127, code n = q ^ seg.
// So LDS (lane-linear DMA copy of this) has granule p = seg*128 + (n ^ seg):
// MFMA read octets (col 0..7, seg const) -> bank-groups (col^seg)&7 distinct.
__global__ void vq_prep_sw(const float* __restrict__ cb,
                           unsigned short* __restrict__ cbh, unsigned short* __restrict__ cbl) {
    const int chunk = blockIdx.x;          // 64 chunks
    const int nc = (chunk >> 2) * BN;
    const int kc = (chunk & 3) * KC;
    #pragma unroll
    for (int i = 0; i < 4; ++i) {
        const int p   = i * 256 + threadIdx.x;
        const int seg = p >> 7;
        const int n   = (p & 127) ^ seg;
        const float* src = cb + (size_t)(nc + n) * D + kc + seg * 8;
        const float4 f0 = *reinterpret_cast<const float4*>(src);
        const float4 f1 = *reinterpret_cast<const float4*>(src + 4);
        const float f[8] = {f0.x, f0.y, f0.z, f0.w, f1.x, f1.y, f1.z, f1.w};
        v8s h, l;
        #pragma unroll
        for (int j = 0; j < 8; ++j) {
            unsigned short hb = f2bf(f[j]);
            h[j] = (short)hb;
            l[j] = (short)f2bf(f[j] - bf2f(hb));
        }
        const size_t o = ((size_t)chunk * 1024 + p) * 8;
        *reinterpret_cast<v8s*>(cbh + o) = h;
        *reinterpret_cast<v8s*>(cbl + o) = l;
    }
}

// ---------------- kernel 2: MFMA argmin + fused gather/loss ----------------
// Ping-pong LDS double buffer fed by global_load_lds; loads for chunk c+1 are
// issued right after the barrier that opens chunk c, so they fly during c's MFMAs.
__global__ __launch_bounds__(256, 2) void vq_argmin_mfma(
        const float* __restrict__ x, const float* __restrict__ cb,
        const unsigned short* __restrict__ cbh, const unsigned short* __restrict__ cbl,
        const float* __restrict__ c2, float* __restrict__ idx_out,
        float* __restrict__ qout, float* __restrict__ partial, int N) {
    __shared__ unsigned short lds_h[2][BN * 8 * 8];   // 2 x 16 KB
    __shared__ unsigned short lds_l[2][BN * 8 * 8];   // 2 x 16 KB
    __shared__ float red_v[64 * 32];                  // 8 KB
    __shared__ int   red_i[64 * 32];                  // 8 KB   (total 80 KB -> 2 blocks/CU)

    const int tid  = threadIdx.x;
    const int w    = tid >> 6;
    const int lane = tid & 63;
    const int col  = lane & 15;     // MFMA col / A-row selector
    const int quad = lane >> 4;     // k-granule selector
    const int mg   = w >> 1;
    const int ng   = w & 1;
    const int m0   = blockIdx.x * BM;
    const int n_stages = (N >> 7) * 4;

    // per-wave staging pointers: this wave stages granules [w*256, w*256+256)
    const unsigned short* gh0 = cbh + ((size_t)(w * 256 + lane)) * 8;
    const unsigned short* gl0 = cbl + ((size_t)(w * 256 + lane)) * 8;

    // ---- load A-frags: rows m0 + mg*32 + mt*16 + col, full K, hi+lo (128 VGPR) ----
    v8s xh[2][8], xl[2][8];
    #pragma unroll
    for (int mt = 0; mt < 2; ++mt) {
        const float* xr = x + (size_t)(m0 + mg * 32 + mt * 16 + col) * D;
        #pragma unroll
        for (int ks = 0; ks < 8; ++ks) {
            const int kb = ks * 32 + quad * 8;
            const float4 f0 = *reinterpret_cast<const float4*>(xr + kb);
            const float4 f1 = *reinterpret_cast<const float4*>(xr + kb + 4);
            float f[8] = {f0.x, f0.y, f0.z, f0.w, f1.x, f1.y, f1.z, f1.w};
            v8s h, l;
            #pragma unroll
            for (int j = 0; j < 8; ++j) {
                unsigned short hb = f2bf(f[j]);
                h[j] = (short)hb;
                l[j] = (short)f2bf(f[j] - bf2f(hb));
            }
            xh[mt][ks] = h; xl[mt][ks] = l;
        }
    }

    float runmin[2][4];
    int   runidx[2][4];
    #pragma unroll
    for (int mt = 0; mt < 2; ++mt)
        #pragma unroll
        for (int r = 0; r < 4; ++r) { runmin[mt][r] = 3.4e38f; runidx[mt][r] = 0; }

    v4f acc[4][2];
    #pragma unroll
    for (int nt = 0; nt < 4; ++nt)
        #pragma unroll
        for (int mt = 0; mt < 2; ++mt) acc[nt][mt] = 0.0f;

    // issue stage 0
    {
        const unsigned short* gh = gh0;
        const unsigned short* gl = gl0;
        #pragma unroll
        for (int i = 0; i < 4; ++i) {
            gl_lds16(gh + i * 512, &lds_h[0][(w * 256 + i * 64) * 8]);
            gl_lds16(gl + i * 512, &lds_l[0][(w * 256 + i * 64) * 8]);
        }
    }

    for (int c = 0; c < n_stages; ++c) {
        const int par = c & 1;
        __syncthreads();   // vmcnt(0)+barrier: my stage-c loads landed, all waves see them,
                           // and everyone is done computing from buffer (c+1)&1.
        if (c + 1 < n_stages) {
            const unsigned short* gh = gh0 + (size_t)(c + 1) * 8192;
            const unsigned short* gl = gl0 + (size_t)(c + 1) * 8192;
            unsigned short* lh = lds_h[par ^ 1];
            unsigned short* ll = lds_l[par ^ 1];
            #pragma unroll
            for (int i = 0; i < 4; ++i) {
                gl_lds16(gh + i * 512, lh + (w * 256 + i * 64) * 8);
                gl_lds16(gl + i * 512, ll + (w * 256 + i * 64) * 8);
            }
        }

        // compute chunk c: kc = (c&3)*64, 2 k-steps
        #pragma unroll
        for (int ksk = 0; ksk < 2; ++ksk) {
            const int ks  = (c & 3) * 2 + ksk;      // global k-step 0..7
            const int seg = ksk * 4 + quad;         // 0..7
            #pragma unroll
            for (int nt = 0; nt < 4; ++nt) {
                const int p = seg * BN + ((ng * 64 + nt * 16 + col) ^ seg);
                const v8s ch = *reinterpret_cast<const v8s*>(&lds_h[par][p * 8]);
                const v8s cl = *reinterpret_cast<const v8s*>(&lds_l[par][p * 8]);
                #pragma unroll
                for (int mt = 0; mt < 2; ++mt) {
                    acc[nt][mt] = MFMA16(xh[mt][ks], ch, acc[nt][mt], 0, 0, 0);
                    acc[nt][mt] = MFMA16(xl[mt][ks], ch, acc[nt][mt], 0, 0, 0);
                    acc[nt][mt] = MFMA16(xh[mt][ks], cl, acc[nt][mt], 0, 0, 0);
                }
            }
        }

        if ((c & 3) == 3) {   // finalize this nc group
            const int nc = (c >> 2) * BN;
            #pragma unroll
            for (int nt = 0; nt < 4; ++nt) {
                const int n   = nc + ng * 64 + nt * 16 + col;
                const float c2n = c2[n];
                #pragma unroll
                for (int mt = 0; mt < 2; ++mt) {
                    #pragma unroll
                    for (int r = 0; r < 4; ++r) {
                        const float s = c2n - 2.0f * acc[nt][mt][r];
                        if (s < runmin[mt][r]) { runmin[mt][r] = s; runidx[mt][r] = n; }
                    }
                    acc[nt][mt] = 0.0f;
                }
            }
        }
    }

    // ---- merge: row = mg*32 + mt*16 + quad*4 + r ; slot = ng*16 + col (swizzled) ----
    __syncthreads();
    #pragma unroll
    for (int mt = 0; mt < 2; ++mt)
        #pragma unroll
        for (int r = 0; r < 4; ++r) {
            const int row  = mg * 32 + mt * 16 + quad * 4 + r;
            const int slot = (ng * 16 + col) ^ (row & 31);
            red_v[row * 32 + slot] = runmin[mt][r];
            red_i[row * 32 + slot] = runidx[mt][r];
        }
    __syncthreads();
    float best = 3.4e38f;
    int   bidx = 0;
    if (tid < 64) {
        #pragma unroll 4
        for (int t = 0; t < 32; ++t) {
            const int  sl = t ^ (tid & 31);
            const float v = red_v[tid * 32 + sl];
            const int  id = red_i[tid * 32 + sl];
            if (v < best || (v == best && id < bidx)) { best = v; bidx = id; }
        }
        idx_out[m0 + tid] = (float)bidx;
    }
    __syncthreads();
    int* idx_sh = reinterpret_cast<int*>(red_v);
    if (tid < 64) idx_sh[tid] = bidx;
    __syncthreads();

    // ---- fused gather + loss over this block's 64 rows (x tile is L2-hot) ----
    const float* xg2 = x + (size_t)m0 * D;
    float s = 0.0f;
    #pragma unroll
    for (int i = 0; i < 16; ++i) {
        const int g   = i * 256 + tid;      // float4-granule, 4096 total
        const int row = g >> 6;
        const int k4  = (g & 63) * 4;
        const int idx = idx_sh[row];
        const float4 c  = *reinterpret_cast<const float4*>(cb  + (size_t)idx * D + k4);
        const float4 xv = *reinterpret_cast<const float4*>(xg2 + (size_t)row * D + k4);
        *reinterpret_cast<float4*>(qout + (size_t)(m0 + row) * D + k4) = c;
        const float dx = c.x - xv.x, dy = c.y - xv.y, dz = c.z - xv.z, dw = c.w - xv.w;
        s += dx * dx + dy * dy + dz * dz + dw * dw;
    }
    #pragma unroll
    for (int off = 32; off > 0; off >>= 1) s += __shfl_down(s, off, 64);
    float* wsum = reinterpret_cast<float*>(red_i);
    if ((tid & 63) == 0) wsum[tid >> 6] = s;
    __syncthreads();
    if (tid == 0) partial[blockIdx.x] = wsum[0] + wsum[1] + wsum[2] + wsum[3];
}

// ---------------- kernel 3: final loss reduction ----------------
__global__ void vq_reduce_kernel(const float* __restrict__ partial, float* __restrict__ loss,
                                 float scale, int n) {
    __shared__ float red[4];
    const int tid = threadIdx.x;
    float s = 0.0f;
    for (int i = tid; i < n; i += 256) s += partial[i];
    #pragma unroll
    for (int off = 32; off > 0; off >>= 1) s += __shfl_down(s, off, 64);
    if ((tid & 63) == 0) red[tid >> 6] = s;
    __syncthreads();
    if (tid == 0) loss[0] = (red[0] + red[1] + red[2] + red[3]) * scale;
}

extern "C" void kernel_launch(void* const* d_in, const int* in_sizes, int n_in,
                              void* d_out, int out_size, void* d_ws, size_t ws_size,
                              hipStream_t stream) {
    const float* x  = (const float*)d_in[0];
    const float* cb = (const float*)d_in[1];
    const int M = in_sizes[0] / D;   // 32768
    const int N = in_sizes[1] / D;   // 2048

    float* qout    = (float*)d_out;
    float* idx_out = qout + (size_t)M * D;
    float* loss    = idx_out + M;

    // ws layout (bytes): c2 [0,8K) | cbh_sw [8K, +1M) | cbl_sw [+1M) | partial
    char* wsb = (char*)d_ws;
    float*          c2      = (float*)wsb;
    unsigned short* cbh     = (unsigned short*)(wsb + 8192);
    unsigned short* cbl     = cbh + (size_t)N * D;
    float*          partial = (float*)(wsb + 8192 + 2 * (size_t)N * D * sizeof(unsigned short));

    vq_prep_c2<<<N, 64, 0, stream>>>(cb, c2);
    vq_prep_sw<<<(N / BN) * (D / KC), 256, 0, stream>>>(cb, cbh, cbl);
    vq_argmin_mfma<<<M / BM, 256, 0, stream>>>(x, cb, cbh, cbl, c2, idx_out, qout, partial, N);
    const float scale = 2.0f / (float)((size_t)M * D);
    vq_reduce_kernel<<<1, 256, 0, stream>>>(partial, loss, scale, M / BM);
}

// Round 6
// 197.344 us; speedup vs baseline: 1.5146x; 1.5146x over previous
//
#include <hip/hip_runtime.h>

#define D   256
#define BM  64      // rows per block
#define BN  128     // codes per LDS chunk
#define KC  64      // k per LDS chunk (2 MFMA k-steps); 4 chunks per full K

typedef __attribute__((ext_vector_type(8))) short v8s;   // 8 bf16 = 4 VGPR
typedef __attribute__((ext_vector_type(4))) float v4f;
#define MFMA16 __builtin_amdgcn_mfma_f32_16x16x32_bf16

static __device__ inline unsigned short f2bf(float f) {          // RNE
    unsigned u = __float_as_uint(f);
    return (unsigned short)((u + 0x7fffu + ((u >> 16) & 1u)) >> 16);
}
static __device__ inline float bf2f(unsigned short s) {
    return __uint_as_float(((unsigned)s) << 16);
}

// async global->LDS, 16 B per lane. LDS dest must be wave-uniform (HW adds lane*16).
static __device__ inline void gl_lds16(const unsigned short* g, unsigned short* l) {
    __builtin_amdgcn_global_load_lds(
        (const __attribute__((address_space(1))) unsigned int*)g,
        (__attribute__((address_space(3))) unsigned int*)l, 16, 0, 0);
}

// ---------------- kernel 1a: exact c2 ----------------
__global__ void vq_prep_c2(const float* __restrict__ cb, float* __restrict__ c2) {
    const int row  = blockIdx.x;
    const int lane = threadIdx.x;  // 64
    const float4 v = *reinterpret_cast<const float4*>(cb + (size_t)row * D + lane * 4);
    float s = v.x * v.x + v.y * v.y + v.z * v.z + v.w * v.w;
    #pragma unroll
    for (int off = 32; off > 0; off >>= 1) s += __shfl_down(s, off, 64);
    if (lane == 0) c2[row] = s;
}

// ---------------- kernel 1b: codebook -> bf16 hi/lo, chunk-major pre-swizzled ----------------
// Chunk (nc_i, kc_i) = 128 codes x 64 k = 1024 granules of 16 B (8 bf16).
// Granule p within chunk: seg = p>>7 (k-octet), q = p&127, code n = q ^ seg.
// Lane-linear DMA reproduces this in LDS: MFMA read octets (col 0..7, seg const)
// hit bank-groups (col^seg)&7, all distinct -> conflict-free.
__global__ void vq_prep_sw(const float* __restrict__ cb,
                           unsigned short* __restrict__ cbh, unsigned short* __restrict__ cbl) {
    const int chunk = blockIdx.x;          // 64 chunks
    const int nc = (chunk >> 2) * BN;
    const int kc = (chunk & 3) * KC;
    #pragma unroll
    for (int i = 0; i < 4; ++i) {
        const int p   = i * 256 + threadIdx.x;
        const int seg = p >> 7;
        const int n   = (p & 127) ^ seg;
        const float* src = cb + (size_t)(nc + n) * D + kc + seg * 8;
        const float4 f0 = *reinterpret_cast<const float4*>(src);
        const float4 f1 = *reinterpret_cast<const float4*>(src + 4);
        const float f[8] = {f0.x, f0.y, f0.z, f0.w, f1.x, f1.y, f1.z, f1.w};
        v8s h, l;
        #pragma unroll
        for (int j = 0; j < 8; ++j) {
            unsigned short hb = f2bf(f[j]);
            h[j] = (short)hb;
            l[j] = (short)f2bf(f[j] - bf2f(hb));
        }
        const size_t o = ((size_t)chunk * 1024 + p) * 8;
        *reinterpret_cast<v8s*>(cbh + o) = h;
        *reinterpret_cast<v8s*>(cbl + o) = l;
    }
}

// ---------------- kernel 2: MFMA argmin + fused gather/loss ----------------
// Ping-pong LDS double buffer fed by global_load_lds; loads for stage s+1 are
// issued right after the barrier opening stage s, flying during s's MFMAs.
// The 4 k-chunks per n-group are #pragma-unrolled so all register-array
// indices (fragment ks, buffer parity) are compile-time — no scratch spill.
__global__ __launch_bounds__(256, 2) void vq_argmin_mfma(
        const float* __restrict__ x, const float* __restrict__ cb,
        const unsigned short* __restrict__ cbh, const unsigned short* __restrict__ cbl,
        const float* __restrict__ c2, float* __restrict__ idx_out,
        float* __restrict__ qout, float* __restrict__ partial, int N) {
    __shared__ unsigned short lds_h[2][BN * 8 * 8];   // 2 x 16 KB
    __shared__ unsigned short lds_l[2][BN * 8 * 8];   // 2 x 16 KB
    __shared__ float red_v[64 * 32];                  // 8 KB
    __shared__ int   red_i[64 * 32];                  // 8 KB   (total 80 KB -> 2 blocks/CU)

    const int tid  = threadIdx.x;
    const int w    = tid >> 6;
    const int lane = tid & 63;
    const int col  = lane & 15;     // MFMA col / A-row selector
    const int quad = lane >> 4;     // k-granule selector
    const int mg   = w >> 1;
    const int ng   = w & 1;
    const int m0   = blockIdx.x * BM;
    const int n_groups = N >> 7;
    const int n_stages = n_groups * 4;

    // per-wave staging pointers: this wave stages granules [w*256, w*256+256)
    const unsigned short* gh0 = cbh + ((size_t)(w * 256 + lane)) * 8;
    const unsigned short* gl0 = cbl + ((size_t)(w * 256 + lane)) * 8;

    // issue stage-0 DMA first: it flies while we convert A-fragments below
    #pragma unroll
    for (int i = 0; i < 4; ++i) {
        gl_lds16(gh0 + i * 512, &lds_h[0][(w * 256 + i * 64) * 8]);
        gl_lds16(gl0 + i * 512, &lds_l[0][(w * 256 + i * 64) * 8]);
    }

    // ---- load A-frags: rows m0 + mg*32 + mt*16 + col, full K, hi+lo (128 VGPR) ----
    v8s xh[2][8], xl[2][8];
    #pragma unroll
    for (int mt = 0; mt < 2; ++mt) {
        const float* xr = x + (size_t)(m0 + mg * 32 + mt * 16 + col) * D;
        #pragma unroll
        for (int ks = 0; ks < 8; ++ks) {
            const int kb = ks * 32 + quad * 8;
            const float4 f0 = *reinterpret_cast<const float4*>(xr + kb);
            const float4 f1 = *reinterpret_cast<const float4*>(xr + kb + 4);
            float f[8] = {f0.x, f0.y, f0.z, f0.w, f1.x, f1.y, f1.z, f1.w};
            v8s h, l;
            #pragma unroll
            for (int j = 0; j < 8; ++j) {
                unsigned short hb = f2bf(f[j]);
                h[j] = (short)hb;
                l[j] = (short)f2bf(f[j] - bf2f(hb));
            }
            xh[mt][ks] = h; xl[mt][ks] = l;
        }
    }

    float runmin[2][4];
    int   runidx[2][4];
    #pragma unroll
    for (int mt = 0; mt < 2; ++mt)
        #pragma unroll
        for (int r = 0; r < 4; ++r) { runmin[mt][r] = 3.4e38f; runidx[mt][r] = 0; }

    v4f acc[4][2];
    #pragma unroll
    for (int nt = 0; nt < 4; ++nt)
        #pragma unroll
        for (int mt = 0; mt < 2; ++mt) acc[nt][mt] = 0.0f;

    for (int g = 0; g < n_groups; ++g) {
        #pragma unroll
        for (int cc = 0; cc < 4; ++cc) {           // compile-time chunk index
            const int par   = cc & 1;              // static buffer parity
            const int stage = g * 4 + cc;
            __syncthreads();   // vmcnt(0)+barrier: stage loads landed, all waves
                               // done computing from buffer par^1.
            if (stage + 1 < n_stages) {
                const unsigned short* gh = gh0 + (size_t)(stage + 1) * 8192;
                const unsigned short* gl = gl0 + (size_t)(stage + 1) * 8192;
                unsigned short* lh = lds_h[par ^ 1];
                unsigned short* ll = lds_l[par ^ 1];
                #pragma unroll
                for (int i = 0; i < 4; ++i) {
                    gl_lds16(gh + i * 512, lh + (w * 256 + i * 64) * 8);
                    gl_lds16(gl + i * 512, ll + (w * 256 + i * 64) * 8);
                }
            }

            #pragma unroll
            for (int ksk = 0; ksk < 2; ++ksk) {
                const int ks  = cc * 2 + ksk;       // static 0..7
                const int seg = ksk * 4 + quad;     // 0..7
                #pragma unroll
                for (int nt = 0; nt < 4; ++nt) {
                    const int p = seg * BN + ((ng * 64 + nt * 16 + col) ^ seg);
                    const v8s ch = *reinterpret_cast<const v8s*>(&lds_h[par][p * 8]);
                    const v8s cl = *reinterpret_cast<const v8s*>(&lds_l[par][p * 8]);
                    #pragma unroll
                    for (int mt = 0; mt < 2; ++mt) {
                        acc[nt][mt] = MFMA16(xh[mt][ks], ch, acc[nt][mt], 0, 0, 0);
                        acc[nt][mt] = MFMA16(xl[mt][ks], ch, acc[nt][mt], 0, 0, 0);
                        acc[nt][mt] = MFMA16(xh[mt][ks], cl, acc[nt][mt], 0, 0, 0);
                    }
                }
            }
        }

        // finalize this n-group
        const int nc = g * BN;
        #pragma unroll
        for (int nt = 0; nt < 4; ++nt) {
            const int n   = nc + ng * 64 + nt * 16 + col;
            const float c2n = c2[n];
            #pragma unroll
            for (int mt = 0; mt < 2; ++mt) {
                #pragma unroll
                for (int r = 0; r < 4; ++r) {
                    const float s = c2n - 2.0f * acc[nt][mt][r];
                    if (s < runmin[mt][r]) { runmin[mt][r] = s; runidx[mt][r] = n; }
                }
                acc[nt][mt] = 0.0f;
            }
        }
    }

    // ---- merge: row = mg*32 + mt*16 + quad*4 + r ; slot = ng*16 + col (swizzled) ----
    __syncthreads();
    #pragma unroll
    for (int mt = 0; mt < 2; ++mt)
        #pragma unroll
        for (int r = 0; r < 4; ++r) {
            const int row  = mg * 32 + mt * 16 + quad * 4 + r;
            const int slot = (ng * 16 + col) ^ (row & 31);
            red_v[row * 32 + slot] = runmin[mt][r];
            red_i[row * 32 + slot] = runidx[mt][r];
        }
    __syncthreads();
    float best = 3.4e38f;
    int   bidx = 0;
    if (tid < 64) {
        #pragma unroll 4
        for (int t = 0; t < 32; ++t) {
            const int  sl = t ^ (tid & 31);
            const float v = red_v[tid * 32 + sl];
            const int  id = red_i[tid * 32 + sl];
            if (v < best || (v == best && id < bidx)) { best = v; bidx = id; }
        }
        idx_out[m0 + tid] = (float)bidx;
    }
    __syncthreads();
    int* idx_sh = reinterpret_cast<int*>(red_v);
    if (tid < 64) idx_sh[tid] = bidx;
    __syncthreads();

    // ---- fused gather + loss over this block's 64 rows (x tile is L2-hot) ----
    const float* xg2 = x + (size_t)m0 * D;
    float s = 0.0f;
    #pragma unroll
    for (int i = 0; i < 16; ++i) {
        const int g   = i * 256 + tid;      // float4-granule, 4096 total
        const int row = g >> 6;
        const int k4  = (g & 63) * 4;
        const int idx = idx_sh[row];
        const float4 c  = *reinterpret_cast<const float4*>(cb  + (size_t)idx * D + k4);
        const float4 xv = *reinterpret_cast<const float4*>(xg2 + (size_t)row * D + k4);
        *reinterpret_cast<float4*>(qout + (size_t)(m0 + row) * D + k4) = c;
        const float dx = c.x - xv.x, dy = c.y - xv.y, dz = c.z - xv.z, dw = c.w - xv.w;
        s += dx * dx + dy * dy + dz * dz + dw * dw;
    }
    #pragma unroll
    for (int off = 32; off > 0; off >>= 1) s += __shfl_down(s, off, 64);
    float* wsum = reinterpret_cast<float*>(red_i);
    if ((tid & 63) == 0) wsum[tid >> 6] = s;
    __syncthreads();
    if (tid == 0) partial[blockIdx.x] = wsum[0] + wsum[1] + wsum[2] + wsum[3];
}

// ---------------- kernel 3: final loss reduction ----------------
__global__ void vq_reduce_kernel(const float* __restrict__ partial, float* __restrict__ loss,
                                 float scale, int n) {
    __shared__ float red[4];
    const int tid = threadIdx.x;
    float s = 0.0f;
    for (int i = tid; i < n; i += 256) s += partial[i];
    #pragma unroll
    for (int off = 32; off > 0; off >>= 1) s += __shfl_down(s, off, 64);
    if ((tid & 63) == 0) red[tid >> 6] = s;
    __syncthreads();
    if (tid == 0) loss[0] = (red[0] + red[1] + red[2] + red[3]) * scale;
}

extern "C" void kernel_launch(void* const* d_in, const int* in_sizes, int n_in,
                              void* d_out, int out_size, void* d_ws, size_t ws_size,
                              hipStream_t stream) {
    const float* x  = (const float*)d_in[0];
    const float* cb = (const float*)d_in[1];
    const int M = in_sizes[0] / D;   // 32768
    const int N = in_sizes[1] / D;   // 2048

    float* qout    = (float*)d_out;
    float* idx_out = qout + (size_t)M * D;
    float* loss    = idx_out + M;

    // ws layout (bytes): c2 [0,8K) | cbh_sw [8K, +1M) | cbl_sw [+1M) | partial
    char* wsb = (char*)d_ws;
    float*          c2      = (float*)wsb;
    unsigned short* cbh     = (unsigned short*)(wsb + 8192);
    unsigned short* cbl     = cbh + (size_t)N * D;
    float*          partial = (float*)(wsb + 8192 + 2 * (size_t)N * D * sizeof(unsigned short));

    vq_prep_c2<<<N, 64, 0, stream>>>(cb, c2);
    vq_prep_sw<<<(N / BN) * (D / KC), 256, 0, stream>>>(cb, cbh, cbl);
    vq_argmin_mfma<<<M / BM, 256, 0, stream>>>(x, cb, cbh, cbl, c2, idx_out, qout, partial, N);
    const float scale = 2.0f / (float)((size_t)M * D);
    vq_reduce_kernel<<<1, 256, 0, stream>>>(partial, loss, scale, M / BM);
}